// Round 1
// 1253.657 us; speedup vs baseline: 1.1072x; 1.1072x over previous
//
#include <hip/hip_runtime.h>

typedef unsigned long long u64;
typedef unsigned int u32;
typedef unsigned short u16;

typedef __attribute__((ext_vector_type(8))) short short8;
typedef __attribute__((ext_vector_type(4))) short short4v;
typedef __attribute__((ext_vector_type(4))) float floatx4;

static constexpr int BROWS = 4096;   // batch rows (M)
static constexpr int ENUM_ = 16384;  // num embeddings (N)
static constexpr int KD    = 4096;   // embedding dim (K)
static constexpr int CANDMAX = 65536;
#define MARGIN 4e-4f

// ---------- helpers ----------

__device__ __forceinline__ u32 sortable(float d) {
  u32 u = __float_as_uint(d);
  return (u & 0x80000000u) ? ~u : (u | 0x80000000u);
}
__device__ __forceinline__ float unsortable(u32 k) {
  u32 u = (k & 0x80000000u) ? (k & 0x7fffffffu) : ~k;
  return __uint_as_float(u);
}

__device__ __forceinline__ u16 f2bf_rn(float f) {
  u32 u = __float_as_uint(f);
  u32 r = (u + 0x7fffu + ((u >> 16) & 1u)) >> 16;   // RNE (no NaNs in data)
  return (u16)r;
}
__device__ __forceinline__ float bf2f(u16 h) {
  return __uint_as_float((u32)h << 16);
}

__device__ __forceinline__ void gload_lds16(const void* g, void* l) {
  __builtin_amdgcn_global_load_lds((const __attribute__((address_space(1))) void*)g,
                                   (__attribute__((address_space(3))) void*)l,
                                   16, 0, 0);
}

__device__ __forceinline__ float blockReduceSumF(float v) {
  __shared__ float s[4];
  #pragma unroll
  for (int o = 32; o > 0; o >>= 1) v += __shfl_down(v, o);
  int lane = threadIdx.x & 63, wid = threadIdx.x >> 6;
  if (lane == 0) s[wid] = v;
  __syncthreads();
  float r = 0.f;
  if (threadIdx.x == 0) r = s[0] + s[1] + s[2] + s[3];
  return r;
}

__device__ __forceinline__ double blockReduceSumD(double v) {
  __shared__ double s[4];
  #pragma unroll
  for (int o = 32; o > 0; o >>= 1) v += __shfl_down(v, o);
  int lane = threadIdx.x & 63, wid = threadIdx.x >> 6;
  if (lane == 0) s[wid] = v;
  __syncthreads();
  double r = 0.0;
  if (threadIdx.x == 0) r = s[0] + s[1] + s[2] + s[3];
  return r;
}

// ---------- precompute kernels ----------

// x: fp32 -> bf16 hi only (8 elems / thread)
__global__ __launch_bounds__(256) void split_hi(const float* __restrict__ src,
                                                u16* __restrict__ hi, int n8) {
  int t = blockIdx.x * 256 + threadIdx.x;
  if (t >= n8) return;
  const float4* s = (const float4*)src + (size_t)t * 2;
  float4 a = s[0], b = s[1];
  float v[8] = {a.x, a.y, a.z, a.w, b.x, b.y, b.z, b.w};
  short h[8];
  #pragma unroll
  for (int i = 0; i < 8; ++i) h[i] = (short)f2bf_rn(v[i]);
  *(short8*)(hi + (size_t)t * 8) = *(short8*)h;
}

// w: fp32 -> bf16 hi, fused with e2[j]=sum w^2 (fp32, same tree as before).
__global__ __launch_bounds__(256) void split_w_e2(const float* __restrict__ w,
                                                  u16* __restrict__ hi,
                                                  float* __restrict__ e2) {
  int j = blockIdx.x;
  const float4* wr = (const float4*)(w + (size_t)j * KD);
  u16* hr = hi + (size_t)j * KD;
  float local = 0.f;
  #pragma unroll
  for (int t = 0; t < 4; ++t) {
    int e = threadIdx.x + t * 256;
    float4 v = wr[e];
    local += v.x * v.x + v.y * v.y + v.z * v.z + v.w * v.w;
    short h[4] = {(short)f2bf_rn(v.x), (short)f2bf_rn(v.y),
                  (short)f2bf_rn(v.z), (short)f2bf_rn(v.w)};
    *(short4v*)(hr + (size_t)e * 4) = *(short4v*)h;
  }
  float tot = blockReduceSumF(local);
  if (threadIdx.x == 0) e2[j] = tot;
}

// fp32 -> bf16 hi + lo (for 3-term fallback)
__global__ __launch_bounds__(256) void split_kernel(const float* __restrict__ src,
                                                    u16* __restrict__ hi,
                                                    u16* __restrict__ lo, int n8) {
  int t = blockIdx.x * 256 + threadIdx.x;
  if (t >= n8) return;
  const float4* s = (const float4*)src + (size_t)t * 2;
  float4 a = s[0], b = s[1];
  float v[8] = {a.x, a.y, a.z, a.w, b.x, b.y, b.z, b.w};
  short h[8], l[8];
  #pragma unroll
  for (int i = 0; i < 8; ++i) {
    u16 hh = f2bf_rn(v[i]);
    h[i] = (short)hh;
    l[i] = (short)f2bf_rn(v[i] - bf2f(hh));
  }
  *(short8*)(hi + (size_t)t * 8) = *(short8*)h;
  *(short8*)(lo + (size_t)t * 8) = *(short8*)l;
}

// e2 standalone (fallback paths)
__global__ __launch_bounds__(256) void e2_kernel(const float* __restrict__ w,
                                                 float* __restrict__ e2) {
  int j = blockIdx.x;
  const float4* wr = (const float4*)(w + (size_t)j * KD);
  float local = 0.f;
  #pragma unroll
  for (int t = 0; t < 4; ++t) {
    float4 v = wr[threadIdx.x + t * 256];
    local += v.x * v.x + v.y * v.y + v.z * v.z + v.w * v.w;
  }
  float tot = blockReduceSumF(local);
  if (threadIdx.x == 0) e2[j] = tot;
}

// ---------- pass 1: hi*hi MFMA GEMM, 256x256 tile, 8-phase counted-vmcnt ----
// 512 threads = 8 waves (2 M x 4 N), per-wave output 128x64 (8x4 16x16 frags).
// BK=64 split into two K-halves (Ak0/Ak1/Bk0/Bk1, 16 KB each). LDS = 2 bufs x
// 64 KB = 128 KB. Phase c: ks=c>>1, mh=c&1; reads only K-half ks, so a tile's
// halves staged >=4 phases before first read -> single s_waitcnt vmcnt(4) per
// K-tile (never 0: counted-vmcnt pipeline, T3+T4), setprio around MFMA (T5).
// LDS chunk bijection: region chunk c = m*4 + (g ^ ((m>>1)&3)) -> frag reads
// are 2 lanes/bank (free), global_load_lds dest stays linear (lane x 16 B).
// Stage issue schedule per tile t phase c: c0:Ak1(t+1) c1:Bk1(t+1)
// c2:Ak0(t+2) c3:Bk0(t+2); every region has >=1 barrier between last read and
// next DMA issue; vmcnt(4) at c3 guarantees tile t+1 fully landed.
__global__ __launch_bounds__(512, 2)
void gemm_hi8(const u16* __restrict__ Ah, const u16* __restrict__ Bh,
              const float* __restrict__ e2, u16* __restrict__ dist,
              u64* __restrict__ best) {
  __shared__ char smem[131072];
  constexpr int NT = KD / 64;  // 64 K-tiles

  // XCD-aware bijective swizzle (1024 blocks, 8 XCDs, 1024%8==0)
  const u32 wg = blockIdx.x;
  const u32 swz = (wg & 7) * 128 + (wg >> 3);
  const int by = swz & 15;     // M tile fast -> neighbors share B panel
  const int bx = swz >> 4;
  const int row0 = by * 256, col0 = bx * 256;

  const int t = threadIdx.x;
  const int lane = t & 63, wv = t >> 6;
  const int wr = wv >> 2, wc = wv & 3;       // 2 x 4 wave grid
  const int quad = lane >> 4, lcol = lane & 15;

  // staging constants: thread handles chunks c=t (m0) and c=t+512 (m0+128),
  // same source k-chunk g for both.
  const int m0 = t >> 2;
  const int g0 = (t & 3) ^ ((t >> 3) & 3);
  const size_t aG0 = (size_t)(row0 + m0) * KD + g0 * 8;
  const size_t bG0 = (size_t)(col0 + m0) * KD + g0 * 8;
  const size_t rowStep = (size_t)128 * KD;

  // kinds: 0=Ak0 (off 0), 1=Bk0 (32768), 2=Ak1 (16384), 3=Bk1 (49152)
  auto stage = [&](int tau, int k) {
    if (tau >= NT) return;
    char* base = smem + (tau & 1) * 65536 +
                 (k == 0 ? 0 : (k == 1 ? 32768 : (k == 2 ? 16384 : 49152)));
    size_t gofs = ((k == 0 || k == 2) ? aG0 : bG0) +
                  (size_t)tau * 64 + (k >= 2 ? 32 : 0);
    const u16* src = (k == 0 || k == 2) ? Ah : Bh;
    gload_lds16(src + gofs, base + t * 16);
    gload_lds16(src + gofs + rowStep, base + t * 16 + 8192);
  };

  // prologue: tile 0 fully + first K-half of tile 1; wait so tile 0 landed
  stage(0, 0); stage(0, 1); stage(0, 2); stage(0, 3);
  stage(1, 0); stage(1, 1);
  asm volatile("s_waitcnt vmcnt(4)" ::: "memory");
  asm volatile("s_barrier" ::: "memory");

  floatx4 acc[8][4] = {};

  for (int tt = 0; tt < NT; ++tt) {
    char* buf = smem + (tt & 1) * 65536;
    short8 bf[4];
    #pragma unroll
    for (int c = 0; c < 4; ++c) {
      const int ks = c >> 1, mh = c & 1;
      const char* Ar = buf + ks * 16384;
      const char* Br = buf + 32768 + ks * 16384;

      short8 af[4];
      #pragma unroll
      for (int r = 0; r < 4; ++r) {
        int m = wr * 128 + mh * 64 + r * 16 + lcol;
        af[r] = *(const short8*)(Ar + m * 64 + ((quad ^ ((m >> 1) & 3)) << 4));
      }
      if (mh == 0) {   // B frags loaded once per K-half, reused next phase
        #pragma unroll
        for (int n = 0; n < 4; ++n) {
          int mm = wc * 64 + n * 16 + lcol;
          bf[n] = *(const short8*)(Br + mm * 64 + ((quad ^ ((mm >> 1) & 3)) << 4));
        }
      }

      if (c == 0)      stage(tt + 1, 2);
      else if (c == 1) stage(tt + 1, 3);
      else if (c == 2) stage(tt + 2, 0);
      else             stage(tt + 2, 1);

      asm volatile("s_barrier" ::: "memory");
      __builtin_amdgcn_s_setprio(1);
      #pragma unroll
      for (int r = 0; r < 4; ++r)
        #pragma unroll
        for (int n = 0; n < 4; ++n)
          acc[mh * 4 + r][n] = __builtin_amdgcn_mfma_f32_16x16x32_bf16(
              af[r], bf[n], acc[mh * 4 + r][n], 0, 0, 0);
      __builtin_amdgcn_s_setprio(0);
      if (c == 3) asm volatile("s_waitcnt vmcnt(4)" ::: "memory");
      asm volatile("s_barrier" ::: "memory");
    }
  }

  // epilogue: C/D layout col=lane&15, row=quad*4+reg. dist stored as bf16
  // (quant err ~1.5e-5 << MARGIN; row-min kept in fp32 via key).
  float e2v[4];
  #pragma unroll
  for (int n = 0; n < 4; ++n) e2v[n] = e2[col0 + wc * 64 + n * 16 + lcol];

  #pragma unroll
  for (int fm = 0; fm < 8; ++fm) {
    #pragma unroll
    for (int i = 0; i < 4; ++i) {
      int grow = row0 + wr * 128 + fm * 16 + quad * 4 + i;
      u64 kmin = ~0ull;
      #pragma unroll
      for (int n = 0; n < 4; ++n) {
        int gcol = col0 + wc * 64 + n * 16 + lcol;
        float d = __fadd_rn(e2v[n], __fmul_rn(-2.0f, acc[fm][n][i]));
        dist[(size_t)grow * ENUM_ + gcol] = f2bf_rn(d);
        u64 key = ((u64)sortable(d) << 32) | (u32)gcol;
        kmin = key < kmin ? key : kmin;
      }
      #pragma unroll
      for (int msk = 1; msk < 16; msk <<= 1) {
        u64 o = __shfl_xor(kmin, msk);
        kmin = o < kmin ? o : kmin;
      }
      if (lcol == 0) atomicMin(&best[grow], kmin);
    }
  }
}

// ---------- pass 2: scan bf16 d-hat, emit candidates within margin ----------
__global__ __launch_bounds__(256)
void scan_kernel(const u16* __restrict__ dist, const u64* __restrict__ best,
                 u64* __restrict__ cand, int* __restrict__ ccount) {
  const int n8 = BROWS * ENUM_ / 8;
  int step = gridDim.x * 256;
  for (int f = blockIdx.x * 256 + threadIdx.x; f < n8; f += step) {
    int i = f >> 11;                       // 2048 short8 per row
    float limit = unsortable((u32)(best[i] >> 32)) + MARGIN;
    short8 v = ((const short8*)dist)[f];
    #pragma unroll
    for (int e = 0; e < 8; ++e) {
      float d = bf2f((u16)v[e]);
      if (d <= limit) {
        int pos = atomicAdd(ccount, 1);
        if (pos < CANDMAX) cand[pos] = ((u64)(u32)i << 32) | (u32)(f * 8 + e - i * ENUM_);
      }
    }
  }
}

// ---------- pass 3: exact fp64 rescore of candidates ----------
__global__ __launch_bounds__(256)
void refine_kernel(const float* __restrict__ x, const float* __restrict__ w,
                   const u64* __restrict__ cand, const int* __restrict__ ccount,
                   u64* __restrict__ best2) {
  int cnt = *ccount;
  if (cnt > CANDMAX) cnt = CANDMAX;
  for (int b = blockIdx.x; b < cnt; b += gridDim.x) {
    u64 cd = cand[b];
    int i = (int)(cd >> 32), j = (int)(cd & 0xffffffffu);
    const float4* xr = (const float4*)(x + (size_t)i * KD);
    const float4* wr = (const float4*)(w + (size_t)j * KD);
    double local = 0.0;
    #pragma unroll
    for (int t = 0; t < 4; ++t) {
      int e = threadIdx.x + t * 256;
      float4 xv = xr[e], wv = wr[e];
      local += (double)wv.x * ((double)wv.x - 2.0 * (double)xv.x)
             + (double)wv.y * ((double)wv.y - 2.0 * (double)xv.y)
             + (double)wv.z * ((double)wv.z - 2.0 * (double)xv.z)
             + (double)wv.w * ((double)wv.w - 2.0 * (double)xv.w);
    }
    double d = blockReduceSumD(local);
    if (threadIdx.x == 0) {
      u64 key = ((u64)sortable((float)d) << 32) | (u32)j;
      atomicMin(&best2[i], key);
    }
    __syncthreads();
  }
}

// ---------- 3-term fallback GEMM ----------
__global__ __launch_bounds__(256)
void gemm_argmin_mfma(const u16* __restrict__ Ah, const u16* __restrict__ Al,
                      const u16* __restrict__ Bh, const u16* __restrict__ Bl,
                      const float* __restrict__ e2, u64* __restrict__ best) {
  __shared__ char smem[32768];
  const int by = blockIdx.x, bx = blockIdx.y;
  const int row0 = by * 128, col0 = bx * 128;
  const int t = threadIdx.x;
  const int lane = t & 63, wv = t >> 6;
  const int wr = wv >> 1, wc = wv & 1;
  const int srow = t >> 2;
  const int schunk = (t & 3) ^ ((t >> 3) & 3);
  const size_t aoff0 = (size_t)(row0 + srow) * KD + schunk * 8;
  const size_t aoff1 = aoff0 + (size_t)64 * KD;
  const size_t boff0 = (size_t)(col0 + srow) * KD + schunk * 8;
  const size_t boff1 = boff0 + (size_t)64 * KD;
  char* sAh = smem; char* sAl = smem + 8192;
  char* sBh = smem + 16384; char* sBl = smem + 24576;
  const int d0 = t * 16, d1 = 4096 + t * 16;
  floatx4 acc[4][4] = {};
  for (int kk = 0; kk < KD; kk += 32) {
    __syncthreads();
    gload_lds16(Ah + aoff0 + kk, sAh + d0);
    gload_lds16(Ah + aoff1 + kk, sAh + d1);
    gload_lds16(Al + aoff0 + kk, sAl + d0);
    gload_lds16(Al + aoff1 + kk, sAl + d1);
    gload_lds16(Bh + boff0 + kk, sBh + d0);
    gload_lds16(Bh + boff1 + kk, sBh + d1);
    gload_lds16(Bl + boff0 + kk, sBl + d0);
    gload_lds16(Bl + boff1 + kk, sBl + d1);
    __syncthreads();
    short8 afh[4], afl[4];
    #pragma unroll
    for (int r = 0; r < 4; ++r) {
      int m = wr * 64 + r * 16 + (lane & 15);
      int off = m * 64 + (((lane >> 4) ^ ((m >> 1) & 3)) * 16);
      afh[r] = *(const short8*)(sAh + off);
      afl[r] = *(const short8*)(sAl + off);
    }
    #pragma unroll
    for (int c = 0; c < 4; ++c) {
      int m = wc * 64 + c * 16 + (lane & 15);
      int off = m * 64 + (((lane >> 4) ^ ((m >> 1) & 3)) * 16);
      short8 bfh = *(const short8*)(sBh + off);
      short8 bfl = *(const short8*)(sBl + off);
      #pragma unroll
      for (int r = 0; r < 4; ++r) {
        acc[r][c] = __builtin_amdgcn_mfma_f32_16x16x32_bf16(afh[r], bfh, acc[r][c], 0, 0, 0);
        acc[r][c] = __builtin_amdgcn_mfma_f32_16x16x32_bf16(afl[r], bfh, acc[r][c], 0, 0, 0);
        acc[r][c] = __builtin_amdgcn_mfma_f32_16x16x32_bf16(afh[r], bfl, acc[r][c], 0, 0, 0);
      }
    }
  }
  const int quad = lane >> 4, lcol = lane & 15;
  float e2v[4];
  #pragma unroll
  for (int c = 0; c < 4; ++c) e2v[c] = e2[col0 + wc * 64 + c * 16 + lcol];
  #pragma unroll
  for (int r = 0; r < 4; ++r) {
    #pragma unroll
    for (int i = 0; i < 4; ++i) {
      int grow = row0 + wr * 64 + r * 16 + quad * 4 + i;
      u64 kmin = ~0ull;
      #pragma unroll
      for (int c = 0; c < 4; ++c) {
        int gcol = col0 + wc * 64 + c * 16 + lcol;
        float d = __fadd_rn(e2v[c], __fmul_rn(-2.0f, acc[r][c][i]));
        u64 key = ((u64)sortable(d) << 32) | (u32)gcol;
        kmin = key < kmin ? key : kmin;
      }
      #pragma unroll
      for (int msk = 1; msk < 16; msk <<= 1) {
        u64 o = __shfl_xor(kmin, msk);
        kmin = o < kmin ? o : kmin;
      }
      if (lcol == 0) atomicMin(&best[grow], kmin);
    }
  }
}

// ---------- fp32 fallback GEMM ----------
__global__ __launch_bounds__(256)
void gemm_argmin(const float* __restrict__ A, const float* __restrict__ W,
                 const float* __restrict__ e2, u64* __restrict__ best) {
  __shared__ union {
    struct { float As[8][128]; float Bs[8][128]; } st;
    u64 red[128 * 16];
  } sm;
  const int by = blockIdx.x, bx = blockIdx.y;
  const int tid = threadIdx.x;
  const int tx = tid & 15, ty = tid >> 4;
  const int row0 = by * 128, col0 = bx * 128;
  const int lm = tid >> 1, lk = (tid & 1) * 4;
  const float* Ap = A + (size_t)(row0 + lm) * KD + lk;
  const float* Wp = W + (size_t)(col0 + lm) * KD + lk;
  float acc[8][8];
  #pragma unroll
  for (int r = 0; r < 8; ++r)
    #pragma unroll
    for (int c = 0; c < 8; ++c) acc[r][c] = 0.f;
  for (int kk = 0; kk < KD; kk += 8) {
    float4 av = *(const float4*)(Ap + kk);
    float4 bv = *(const float4*)(Wp + kk);
    __syncthreads();
    sm.st.As[lk + 0][lm] = av.x; sm.st.As[lk + 1][lm] = av.y;
    sm.st.As[lk + 2][lm] = av.z; sm.st.As[lk + 3][lm] = av.w;
    sm.st.Bs[lk + 0][lm] = bv.x; sm.st.Bs[lk + 1][lm] = bv.y;
    sm.st.Bs[lk + 2][lm] = bv.z; sm.st.Bs[lk + 3][lm] = bv.w;
    __syncthreads();
    #pragma unroll
    for (int k = 0; k < 8; ++k) {
      float a[8], b[8];
      *(float4*)&a[0] = *(const float4*)&sm.st.As[k][ty * 8];
      *(float4*)&a[4] = *(const float4*)&sm.st.As[k][ty * 8 + 4];
      *(float4*)&b[0] = *(const float4*)&sm.st.Bs[k][tx * 8];
      *(float4*)&b[4] = *(const float4*)&sm.st.Bs[k][tx * 8 + 4];
      #pragma unroll
      for (int r = 0; r < 8; ++r)
        #pragma unroll
        for (int c = 0; c < 8; ++c)
          acc[r][c] = fmaf(a[r], b[c], acc[r][c]);
    }
  }
  __syncthreads();
  float e2v[8];
  #pragma unroll
  for (int c = 0; c < 8; ++c) e2v[c] = e2[col0 + tx * 8 + c];
  #pragma unroll
  for (int r = 0; r < 8; ++r) {
    u64 bk = ~0ull;
    #pragma unroll
    for (int c = 0; c < 8; ++c) {
      int col = col0 + tx * 8 + c;
      float d = fmaf(-2.0f, acc[r][c], e2v[c]);
      u64 key = ((u64)sortable(d) << 32) | (u32)col;
      bk = key < bk ? key : bk;
    }
    sm.red[(ty * 8 + r) * 16 + tx] = bk;
  }
  __syncthreads();
  if (tid < 128) {
    u64 m = sm.red[tid * 16];
    #pragma unroll
    for (int t2 = 1; t2 < 16; ++t2) {
      u64 v = sm.red[tid * 16 + t2];
      m = v < m ? v : m;
    }
    atomicMin(&best[row0 + tid], m);
  }
}

// ---------- tail kernels ----------

__global__ __launch_bounds__(256) void scatter_kernel(const u64* __restrict__ best,
                                                      int* __restrict__ idx,
                                                      int* __restrict__ counts,
                                                      float* __restrict__ enc) {
  int i = blockIdx.x * 256 + threadIdx.x;
  u64 k = best[i];
  int j = (int)(k & 0xffffffffu);
  idx[i] = j;
  atomicAdd(&counts[j], 1);
  enc[(size_t)i * ENUM_ + j] = 1.0f;
}

__global__ __launch_bounds__(256) void gather_loss(const float* __restrict__ x,
                                                   const float* __restrict__ w,
                                                   const int* __restrict__ idx,
                                                   float* __restrict__ quant,
                                                   double* __restrict__ accum) {
  int i = blockIdx.x;
  int j = idx[i];
  const float4* wr = (const float4*)(w + (size_t)j * KD);
  const float4* xr = (const float4*)(x + (size_t)i * KD);
  float* qr = quant + (size_t)i * KD;
  double local = 0.0;
  #pragma unroll
  for (int t = 0; t < 4; ++t) {
    int e = threadIdx.x + t * 256;
    float4 wv = wr[e];
    float4 xv = xr[e];
    qr[4 * e + 0] = wv.x; qr[4 * e + 1] = wv.y;
    qr[4 * e + 2] = wv.z; qr[4 * e + 3] = wv.w;
    double d0 = (double)wv.x - (double)xv.x;
    double d1 = (double)wv.y - (double)xv.y;
    double d2 = (double)wv.z - (double)xv.z;
    double d3 = (double)wv.w - (double)xv.w;
    local += d0 * d0 + d1 * d1 + d2 * d2 + d3 * d3;
  }
  double tot = blockReduceSumD(local);
  if (threadIdx.x == 0) atomicAdd(accum, tot);
}

__global__ __launch_bounds__(256) void scalars_kernel(const int* __restrict__ counts,
                                                      const double* __restrict__ accum,
                                                      float* __restrict__ loss_out,
                                                      float* __restrict__ perp_out) {
  double local = 0.0;
  for (int j = threadIdx.x; j < ENUM_; j += 256) {
    double p = (double)counts[j] * (1.0 / 4096.0);
    local += p * log(p + 1e-10);
  }
  double s = blockReduceSumD(local);
  if (threadIdx.x == 0) {
    double mean = (*accum) * (1.0 / ((double)BROWS * (double)KD));
    loss_out[0] = (float)(1.25 * mean);
    perp_out[0] = (float)exp(-s);
  }
}

// ---------- launch ----------

extern "C" void kernel_launch(void* const* d_in, const int* in_sizes, int n_in,
                              void* d_out, int out_size, void* d_ws, size_t ws_size,
                              hipStream_t stream) {
  const float* x = (const float*)d_in[0];  // [4096][4096]
  const float* w = (const float*)d_in[1];  // [16384][4096]
  float* out = (float*)d_out;

  char* ws = (char*)d_ws;
  u64* best     = (u64*)ws;                    // 32768
  u64* best2    = (u64*)(ws + 32768);          // 32768
  int* idx      = (int*)(ws + 65536);          // 16384
  int* counts   = (int*)(ws + 81920);          // 65536
  double* accum = (double*)(ws + 147456);      // 8
  int* ccount   = (int*)(ws + 147464);         // 4
  float* e2     = (float*)(ws + 163840);       // 65536
  u64* cand     = (u64*)(ws + 229376);         // 524288
  u16* x_hi     = (u16*)(ws + 753664);                 // 33554432
  u16* w_hi     = (u16*)(ws + 753664 + 33554432ull);   // 134217728
  char* regionR = ws + 753664 + 33554432ull + 134217728ull;  // 168525824
  u16* dist     = (u16*)regionR;               // 134217728 (filter-refine, bf16)
  u16* x_lo     = (u16*)regionR;               // 33554432  (3-term fallback)
  u16* w_lo     = (u16*)(regionR + 33554432ull);       // 134217728
  const size_t NEED_FR = 168525824ull + 134217728ull;  // ~303 MB
  const size_t NEED_3T = 168525824ull + 167772160ull;  // ~336 MB

  float* loss_out = out;
  float* quant    = out + 1;
  float* perp_out = out + 16777217;
  float* enc      = out + 16777218;

  hipMemsetAsync(best, 0xFF, 65536, stream);            // best + best2
  hipMemsetAsync(counts, 0, 65536 + 16, stream);        // counts + accum + ccount
  hipMemsetAsync(enc, 0, (size_t)BROWS * ENUM_ * sizeof(float), stream);

  if (ws_size >= NEED_FR) {
    split_hi<<<BROWS * KD / 8 / 256, 256, 0, stream>>>(x, x_hi, BROWS * KD / 8);
    split_w_e2<<<ENUM_, 256, 0, stream>>>(w, w_hi, e2);
    gemm_hi8<<<1024, 512, 0, stream>>>(x_hi, w_hi, e2, dist, best);
    scan_kernel<<<4096, 256, 0, stream>>>(dist, best, cand, ccount);
    refine_kernel<<<4096, 256, 0, stream>>>(x, w, cand, ccount, best2);
    scatter_kernel<<<BROWS / 256, 256, 0, stream>>>(best2, idx, counts, enc);
  } else if (ws_size >= NEED_3T) {
    e2_kernel<<<ENUM_, 256, 0, stream>>>(w, e2);
    split_kernel<<<BROWS * KD / 8 / 256, 256, 0, stream>>>(x, x_hi, x_lo, BROWS * KD / 8);
    split_kernel<<<ENUM_ * KD / 8 / 256, 256, 0, stream>>>(w, w_hi, w_lo, ENUM_ * KD / 8);
    gemm_argmin_mfma<<<dim3(32, 128), 256, 0, stream>>>(x_hi, x_lo, w_hi, w_lo, e2, best);
    scatter_kernel<<<BROWS / 256, 256, 0, stream>>>(best, idx, counts, enc);
  } else {
    e2_kernel<<<ENUM_, 256, 0, stream>>>(w, e2);
    gemm_argmin<<<dim3(32, 128), 256, 0, stream>>>(x, w, e2, best);
    scatter_kernel<<<BROWS / 256, 256, 0, stream>>>(best, idx, counts, enc);
  }
  gather_loss<<<BROWS, 256, 0, stream>>>(x, w, idx, quant, accum);
  scalars_kernel<<<1, 256, 0, stream>>>(counts, accum, loss_out, perp_out);
}

// Round 2
// 1065.295 us; speedup vs baseline: 1.3030x; 1.1768x over previous
//
#include <hip/hip_runtime.h>

typedef unsigned long long u64;
typedef unsigned int u32;
typedef unsigned short u16;

typedef __attribute__((ext_vector_type(8))) short short8;
typedef __attribute__((ext_vector_type(4))) short short4v;
typedef __attribute__((ext_vector_type(4))) float floatx4;
typedef __attribute__((ext_vector_type(4))) int int4v;

static constexpr int BROWS = 4096;   // batch rows (M)
static constexpr int ENUM_ = 16384;  // num embeddings (N)
static constexpr int KD    = 4096;   // embedding dim (K)
static constexpr int CANDMAX = 65536;
#define MARGIN 6e-4f

// ---------- helpers ----------

__device__ __forceinline__ u32 sortable(float d) {
  u32 u = __float_as_uint(d);
  return (u & 0x80000000u) ? ~u : (u | 0x80000000u);
}
__device__ __forceinline__ float unsortable(u32 k) {
  u32 u = (k & 0x80000000u) ? (k & 0x7fffffffu) : ~k;
  return __uint_as_float(u);
}

__device__ __forceinline__ u16 f2bf_rn(float f) {
  u32 u = __float_as_uint(f);
  u32 r = (u + 0x7fffu + ((u >> 16) & 1u)) >> 16;   // RNE (no NaNs in data)
  return (u16)r;
}
__device__ __forceinline__ float bf2f(u16 h) {
  return __uint_as_float((u32)h << 16);
}

__device__ __forceinline__ void gload_lds16(const void* g, void* l) {
  __builtin_amdgcn_global_load_lds((const __attribute__((address_space(1))) void*)g,
                                   (__attribute__((address_space(3))) void*)l,
                                   16, 0, 0);
}

__device__ __forceinline__ float blockReduceSumF(float v) {
  __shared__ float s[4];
  #pragma unroll
  for (int o = 32; o > 0; o >>= 1) v += __shfl_down(v, o);
  int lane = threadIdx.x & 63, wid = threadIdx.x >> 6;
  if (lane == 0) s[wid] = v;
  __syncthreads();
  float r = 0.f;
  if (threadIdx.x == 0) r = s[0] + s[1] + s[2] + s[3];
  return r;
}

__device__ __forceinline__ double blockReduceSumD(double v) {
  __shared__ double s[4];
  #pragma unroll
  for (int o = 32; o > 0; o >>= 1) v += __shfl_down(v, o);
  int lane = threadIdx.x & 63, wid = threadIdx.x >> 6;
  if (lane == 0) s[wid] = v;
  __syncthreads();
  double r = 0.0;
  if (threadIdx.x == 0) r = s[0] + s[1] + s[2] + s[3];
  return r;
}

// ---------- precompute kernels (i8 filter path) ----------

// x: fp32 -> per-row symmetric int8, sx[i] = rowmax/127
__global__ __launch_bounds__(256) void quant_x(const float* __restrict__ x,
                                               signed char* __restrict__ xq,
                                               float* __restrict__ sx) {
  int i = blockIdx.x;
  const float4* xr = (const float4*)(x + (size_t)i * KD);
  float4 v[4];
  float mx = 0.f;
  #pragma unroll
  for (int t = 0; t < 4; ++t) {
    v[t] = xr[threadIdx.x + t * 256];
    mx = fmaxf(mx, fmaxf(fmaxf(fabsf(v[t].x), fabsf(v[t].y)),
                         fmaxf(fabsf(v[t].z), fabsf(v[t].w))));
  }
  #pragma unroll
  for (int o = 32; o > 0; o >>= 1) mx = fmaxf(mx, __shfl_down(mx, o));
  __shared__ float red[4];
  int lane = threadIdx.x & 63, wid = threadIdx.x >> 6;
  if (lane == 0) red[wid] = mx;
  __syncthreads();
  float m = fmaxf(fmaxf(red[0], red[1]), fmaxf(red[2], red[3]));
  float inv = m > 0.f ? 127.f / m : 0.f;
  u32* qr = (u32*)(xq + (size_t)i * KD);
  #pragma unroll
  for (int t = 0; t < 4; ++t) {
    int e = threadIdx.x + t * 256;
    int q0 = __float2int_rn(v[t].x * inv);
    int q1 = __float2int_rn(v[t].y * inv);
    int q2 = __float2int_rn(v[t].z * inv);
    int q3 = __float2int_rn(v[t].w * inv);
    qr[e] = ((u32)(q0 & 0xff)) | ((u32)(q1 & 0xff) << 8) |
            ((u32)(q2 & 0xff) << 16) | ((u32)(q3 & 0xff) << 24);
  }
  if (threadIdx.x == 0) sx[i] = m * (1.f / 127.f);
}

// w: fp32 -> per-row int8 + sw[j] + e2[j]=sum w^2 (fp32)
__global__ __launch_bounds__(256) void quant_w_e2(const float* __restrict__ w,
                                                  signed char* __restrict__ wq,
                                                  float* __restrict__ sw,
                                                  float* __restrict__ e2) {
  int j = blockIdx.x;
  const float4* wr = (const float4*)(w + (size_t)j * KD);
  float4 v[4];
  float mx = 0.f, s2 = 0.f;
  #pragma unroll
  for (int t = 0; t < 4; ++t) {
    v[t] = wr[threadIdx.x + t * 256];
    s2 += v[t].x * v[t].x + v[t].y * v[t].y + v[t].z * v[t].z + v[t].w * v[t].w;
    mx = fmaxf(mx, fmaxf(fmaxf(fabsf(v[t].x), fabsf(v[t].y)),
                         fmaxf(fabsf(v[t].z), fabsf(v[t].w))));
  }
  #pragma unroll
  for (int o = 32; o > 0; o >>= 1) {
    s2 += __shfl_down(s2, o);
    mx = fmaxf(mx, __shfl_down(mx, o));
  }
  __shared__ float redS[4], redM[4];
  int lane = threadIdx.x & 63, wid = threadIdx.x >> 6;
  if (lane == 0) { redS[wid] = s2; redM[wid] = mx; }
  __syncthreads();
  float m = fmaxf(fmaxf(redM[0], redM[1]), fmaxf(redM[2], redM[3]));
  float inv = m > 0.f ? 127.f / m : 0.f;
  u32* qr = (u32*)(wq + (size_t)j * KD);
  #pragma unroll
  for (int t = 0; t < 4; ++t) {
    int e = threadIdx.x + t * 256;
    int q0 = __float2int_rn(v[t].x * inv);
    int q1 = __float2int_rn(v[t].y * inv);
    int q2 = __float2int_rn(v[t].z * inv);
    int q3 = __float2int_rn(v[t].w * inv);
    qr[e] = ((u32)(q0 & 0xff)) | ((u32)(q1 & 0xff) << 8) |
            ((u32)(q2 & 0xff) << 16) | ((u32)(q3 & 0xff) << 24);
  }
  if (threadIdx.x == 0) {
    sw[j] = m * (1.f / 127.f);
    e2[j] = redS[0] + redS[1] + redS[2] + redS[3];
  }
}

// fp32 -> bf16 hi + lo (3-term fallback)
__global__ __launch_bounds__(256) void split_kernel(const float* __restrict__ src,
                                                    u16* __restrict__ hi,
                                                    u16* __restrict__ lo, int n8) {
  int t = blockIdx.x * 256 + threadIdx.x;
  if (t >= n8) return;
  const float4* s = (const float4*)src + (size_t)t * 2;
  float4 a = s[0], b = s[1];
  float v[8] = {a.x, a.y, a.z, a.w, b.x, b.y, b.z, b.w};
  short h[8], l[8];
  #pragma unroll
  for (int i = 0; i < 8; ++i) {
    u16 hh = f2bf_rn(v[i]);
    h[i] = (short)hh;
    l[i] = (short)f2bf_rn(v[i] - bf2f(hh));
  }
  *(short8*)(hi + (size_t)t * 8) = *(short8*)h;
  *(short8*)(lo + (size_t)t * 8) = *(short8*)l;
}

// e2 standalone (fallback paths)
__global__ __launch_bounds__(256) void e2_kernel(const float* __restrict__ w,
                                                 float* __restrict__ e2) {
  int j = blockIdx.x;
  const float4* wr = (const float4*)(w + (size_t)j * KD);
  float local = 0.f;
  #pragma unroll
  for (int t = 0; t < 4; ++t) {
    float4 v = wr[threadIdx.x + t * 256];
    local += v.x * v.x + v.y * v.y + v.z * v.z + v.w * v.w;
  }
  float tot = blockReduceSumF(local);
  if (threadIdx.x == 0) e2[j] = tot;
}

// ---------- pass 1: i8 MFMA GEMM, 256x256 tile, BK=128, 8-phase ----------
// Same schedule as the round-1 bf16 kernel (verified): 512 thr = 8 waves
// (2Mx4N), per-wave out 128x64. BK=128 as two K-halves of 64 i8 = 64 B rows,
// so every LDS region keeps the 256row x 64B layout and 16B-chunk swizzle
// (chunk g stored at slot g ^ ((row>>1)&3); 2-way bank alias only). Each 16B
// fragment now carries K=64 -> mfma_i32_16x16x64_i8 (2x bf16 rate, exact
// accum). 4 phases/K-tile, 16 MFMA/phase, counted vmcnt(4) once per K-tile.
__global__ __launch_bounds__(512, 2)
void gemm_i8(const signed char* __restrict__ Aq, const signed char* __restrict__ Bq,
             const float* __restrict__ sx, const float* __restrict__ sw,
             const float* __restrict__ e2, u16* __restrict__ dist,
             u64* __restrict__ best) {
  __shared__ char smem[131072];
  constexpr int NT = KD / 128;  // 32 K-tiles

  const u32 wg = blockIdx.x;
  const u32 swz = (wg & 7) * 128 + (wg >> 3);   // XCD-bijective (1024 % 8 == 0)
  const int by = swz & 15;
  const int bx = swz >> 4;
  const int row0 = by * 256, col0 = bx * 256;

  const int t = threadIdx.x;
  const int lane = t & 63, wv = t >> 6;
  const int wr = wv >> 2, wc = wv & 3;
  const int quad = lane >> 4, lcol = lane & 15;

  const int m0 = t >> 2;
  const int g0 = (t & 3) ^ ((t >> 3) & 3);
  const size_t aG0 = (size_t)(row0 + m0) * KD + g0 * 16;
  const size_t bG0 = (size_t)(col0 + m0) * KD + g0 * 16;
  const size_t rowStep = (size_t)128 * KD;

  // kinds: 0=Ak0 (off 0), 1=Bk0 (32768), 2=Ak1 (16384), 3=Bk1 (49152)
  auto stage = [&](int tau, int k) {
    if (tau >= NT) return;
    char* base = smem + (tau & 1) * 65536 +
                 (k == 0 ? 0 : (k == 1 ? 32768 : (k == 2 ? 16384 : 49152)));
    size_t gofs = ((k == 0 || k == 2) ? aG0 : bG0) +
                  (size_t)tau * 128 + (k >= 2 ? 64 : 0);
    const signed char* src = (k == 0 || k == 2) ? Aq : Bq;
    gload_lds16(src + gofs, base + t * 16);
    gload_lds16(src + gofs + rowStep, base + t * 16 + 8192);
  };

  stage(0, 0); stage(0, 1); stage(0, 2); stage(0, 3);
  stage(1, 0); stage(1, 1);
  asm volatile("s_waitcnt vmcnt(4)" ::: "memory");
  asm volatile("s_barrier" ::: "memory");

  int4v acc[8][4] = {};

  for (int tt = 0; tt < NT; ++tt) {
    char* buf = smem + (tt & 1) * 65536;
    int4v bf[4];
    #pragma unroll
    for (int c = 0; c < 4; ++c) {
      const int ks = c >> 1, mh = c & 1;
      const char* Ar = buf + ks * 16384;
      const char* Br = buf + 32768 + ks * 16384;

      int4v af[4];
      #pragma unroll
      for (int r = 0; r < 4; ++r) {
        int m = wr * 128 + mh * 64 + r * 16 + lcol;
        af[r] = *(const int4v*)(Ar + m * 64 + ((quad ^ ((m >> 1) & 3)) << 4));
      }
      if (mh == 0) {
        #pragma unroll
        for (int n = 0; n < 4; ++n) {
          int mm = wc * 64 + n * 16 + lcol;
          bf[n] = *(const int4v*)(Br + mm * 64 + ((quad ^ ((mm >> 1) & 3)) << 4));
        }
      }

      if (c == 0)      stage(tt + 1, 2);
      else if (c == 1) stage(tt + 1, 3);
      else if (c == 2) stage(tt + 2, 0);
      else             stage(tt + 2, 1);

      asm volatile("s_barrier" ::: "memory");
      __builtin_amdgcn_s_setprio(1);
      #pragma unroll
      for (int r = 0; r < 4; ++r)
        #pragma unroll
        for (int n = 0; n < 4; ++n)
          acc[mh * 4 + r][n] = __builtin_amdgcn_mfma_i32_16x16x64_i8(
              af[r], bf[n], acc[mh * 4 + r][n], 0, 0, 0);
      __builtin_amdgcn_s_setprio(0);
      if (c == 3) asm volatile("s_waitcnt vmcnt(4)" ::: "memory");
      asm volatile("s_barrier" ::: "memory");
    }
  }

  // epilogue: d = e2[j] - 2*sx[i]*sw[j]*dot. C/D: col=lane&15, row=quad*4+reg
  float e2v[4], sc2[4];
  #pragma unroll
  for (int n = 0; n < 4; ++n) {
    int gc = col0 + wc * 64 + n * 16 + lcol;
    e2v[n] = e2[gc];
    sc2[n] = -2.0f * sw[gc];
  }

  #pragma unroll
  for (int fm = 0; fm < 8; ++fm) {
    #pragma unroll
    for (int i = 0; i < 4; ++i) {
      int grow = row0 + wr * 128 + fm * 16 + quad * 4 + i;
      float sxr = sx[grow];
      u64 kmin = ~0ull;
      #pragma unroll
      for (int n = 0; n < 4; ++n) {
        int gcol = col0 + wc * 64 + n * 16 + lcol;
        float d = __fadd_rn(e2v[n],
                            __fmul_rn(sc2[n] * sxr, (float)acc[fm][n][i]));
        dist[(size_t)grow * ENUM_ + gcol] = f2bf_rn(d);
        u64 key = ((u64)sortable(d) << 32) | (u32)gcol;
        kmin = key < kmin ? key : kmin;
      }
      #pragma unroll
      for (int msk = 1; msk < 16; msk <<= 1) {
        u64 o = __shfl_xor(kmin, msk);
        kmin = o < kmin ? o : kmin;
      }
      if (lcol == 0) atomicMin(&best[grow], kmin);
    }
  }
}

// ---------- pass 2: scan bf16 d-hat, emit candidates within margin ----------
__global__ __launch_bounds__(256)
void scan_kernel(const u16* __restrict__ dist, const u64* __restrict__ best,
                 u64* __restrict__ cand, int* __restrict__ ccount) {
  const int n8 = BROWS * ENUM_ / 8;
  int step = gridDim.x * 256;
  for (int f = blockIdx.x * 256 + threadIdx.x; f < n8; f += step) {
    int i = f >> 11;                       // 2048 short8 per row
    float limit = unsortable((u32)(best[i] >> 32)) + MARGIN;
    short8 v = ((const short8*)dist)[f];
    #pragma unroll
    for (int e = 0; e < 8; ++e) {
      float d = bf2f((u16)v[e]);
      if (d <= limit) {
        int pos = atomicAdd(ccount, 1);
        if (pos < CANDMAX) cand[pos] = ((u64)(u32)i << 32) | (u32)(f * 8 + e - i * ENUM_);
      }
    }
  }
}

// ---------- pass 3: exact fp64 rescore of candidates ----------
__global__ __launch_bounds__(256)
void refine_kernel(const float* __restrict__ x, const float* __restrict__ w,
                   const u64* __restrict__ cand, const int* __restrict__ ccount,
                   u64* __restrict__ best2) {
  int cnt = *ccount;
  if (cnt > CANDMAX) cnt = CANDMAX;
  for (int b = blockIdx.x; b < cnt; b += gridDim.x) {
    u64 cd = cand[b];
    int i = (int)(cd >> 32), j = (int)(cd & 0xffffffffu);
    const float4* xr = (const float4*)(x + (size_t)i * KD);
    const float4* wr = (const float4*)(w + (size_t)j * KD);
    double local = 0.0;
    #pragma unroll
    for (int t = 0; t < 4; ++t) {
      int e = threadIdx.x + t * 256;
      float4 xv = xr[e], wv = wr[e];
      local += (double)wv.x * ((double)wv.x - 2.0 * (double)xv.x)
             + (double)wv.y * ((double)wv.y - 2.0 * (double)xv.y)
             + (double)wv.z * ((double)wv.z - 2.0 * (double)xv.z)
             + (double)wv.w * ((double)wv.w - 2.0 * (double)xv.w);
    }
    double d = blockReduceSumD(local);
    if (threadIdx.x == 0) {
      u64 key = ((u64)sortable((float)d) << 32) | (u32)j;
      atomicMin(&best2[i], key);
    }
    __syncthreads();
  }
}

// ---------- 3-term fallback GEMM ----------
__global__ __launch_bounds__(256)
void gemm_argmin_mfma(const u16* __restrict__ Ah, const u16* __restrict__ Al,
                      const u16* __restrict__ Bh, const u16* __restrict__ Bl,
                      const float* __restrict__ e2, u64* __restrict__ best) {
  __shared__ char smem[32768];
  const int by = blockIdx.x, bx = blockIdx.y;
  const int row0 = by * 128, col0 = bx * 128;
  const int t = threadIdx.x;
  const int lane = t & 63, wv = t >> 6;
  const int wr = wv >> 1, wc = wv & 1;
  const int srow = t >> 2;
  const int schunk = (t & 3) ^ ((t >> 3) & 3);
  const size_t aoff0 = (size_t)(row0 + srow) * KD + schunk * 8;
  const size_t aoff1 = aoff0 + (size_t)64 * KD;
  const size_t boff0 = (size_t)(col0 + srow) * KD + schunk * 8;
  const size_t boff1 = boff0 + (size_t)64 * KD;
  char* sAh = smem; char* sAl = smem + 8192;
  char* sBh = smem + 16384; char* sBl = smem + 24576;
  const int d0 = t * 16, d1 = 4096 + t * 16;
  floatx4 acc[4][4] = {};
  for (int kk = 0; kk < KD; kk += 32) {
    __syncthreads();
    gload_lds16(Ah + aoff0 + kk, sAh + d0);
    gload_lds16(Ah + aoff1 + kk, sAh + d1);
    gload_lds16(Al + aoff0 + kk, sAl + d0);
    gload_lds16(Al + aoff1 + kk, sAl + d1);
    gload_lds16(Bh + boff0 + kk, sBh + d0);
    gload_lds16(Bh + boff1 + kk, sBh + d1);
    gload_lds16(Bl + boff0 + kk, sBl + d0);
    gload_lds16(Bl + boff1 + kk, sBl + d1);
    __syncthreads();
    short8 afh[4], afl[4];
    #pragma unroll
    for (int r = 0; r < 4; ++r) {
      int m = wr * 64 + r * 16 + (lane & 15);
      int off = m * 64 + (((lane >> 4) ^ ((m >> 1) & 3)) * 16);
      afh[r] = *(const short8*)(sAh + off);
      afl[r] = *(const short8*)(sAl + off);
    }
    #pragma unroll
    for (int c = 0; c < 4; ++c) {
      int m = wc * 64 + c * 16 + (lane & 15);
      int off = m * 64 + (((lane >> 4) ^ ((m >> 1) & 3)) * 16);
      short8 bfh = *(const short8*)(sBh + off);
      short8 bfl = *(const short8*)(sBl + off);
      #pragma unroll
      for (int r = 0; r < 4; ++r) {
        acc[r][c] = __builtin_amdgcn_mfma_f32_16x16x32_bf16(afh[r], bfh, acc[r][c], 0, 0, 0);
        acc[r][c] = __builtin_amdgcn_mfma_f32_16x16x32_bf16(afl[r], bfh, acc[r][c], 0, 0, 0);
        acc[r][c] = __builtin_amdgcn_mfma_f32_16x16x32_bf16(afh[r], bfl, acc[r][c], 0, 0, 0);
      }
    }
  }
  const int quad = lane >> 4, lcol = lane & 15;
  float e2v[4];
  #pragma unroll
  for (int c = 0; c < 4; ++c) e2v[c] = e2[col0 + wc * 64 + c * 16 + lcol];
  #pragma unroll
  for (int r = 0; r < 4; ++r) {
    #pragma unroll
    for (int i = 0; i < 4; ++i) {
      int grow = row0 + wr * 64 + r * 16 + quad * 4 + i;
      u64 kmin = ~0ull;
      #pragma unroll
      for (int c = 0; c < 4; ++c) {
        int gcol = col0 + wc * 64 + c * 16 + lcol;
        float d = __fadd_rn(e2v[c], __fmul_rn(-2.0f, acc[r][c][i]));
        u64 key = ((u64)sortable(d) << 32) | (u32)gcol;
        kmin = key < kmin ? key : kmin;
      }
      #pragma unroll
      for (int msk = 1; msk < 16; msk <<= 1) {
        u64 o = __shfl_xor(kmin, msk);
        kmin = o < kmin ? o : kmin;
      }
      if (lcol == 0) atomicMin(&best[grow], kmin);
    }
  }
}

// ---------- fp32 fallback GEMM ----------
__global__ __launch_bounds__(256)
void gemm_argmin(const float* __restrict__ A, const float* __restrict__ W,
                 const float* __restrict__ e2, u64* __restrict__ best) {
  __shared__ union {
    struct { float As[8][128]; float Bs[8][128]; } st;
    u64 red[128 * 16];
  } sm;
  const int by = blockIdx.x, bx = blockIdx.y;
  const int tid = threadIdx.x;
  const int tx = tid & 15, ty = tid >> 4;
  const int row0 = by * 128, col0 = bx * 128;
  const int lm = tid >> 1, lk = (tid & 1) * 4;
  const float* Ap = A + (size_t)(row0 + lm) * KD + lk;
  const float* Wp = W + (size_t)(col0 + lm) * KD + lk;
  float acc[8][8];
  #pragma unroll
  for (int r = 0; r < 8; ++r)
    #pragma unroll
    for (int c = 0; c < 8; ++c) acc[r][c] = 0.f;
  for (int kk = 0; kk < KD; kk += 8) {
    float4 av = *(const float4*)(Ap + kk);
    float4 bv = *(const float4*)(Wp + kk);
    __syncthreads();
    sm.st.As[lk + 0][lm] = av.x; sm.st.As[lk + 1][lm] = av.y;
    sm.st.As[lk + 2][lm] = av.z; sm.st.As[lk + 3][lm] = av.w;
    sm.st.Bs[lk + 0][lm] = bv.x; sm.st.Bs[lk + 1][lm] = bv.y;
    sm.st.Bs[lk + 2][lm] = bv.z; sm.st.Bs[lk + 3][lm] = bv.w;
    __syncthreads();
    #pragma unroll
    for (int k = 0; k < 8; ++k) {
      float a[8], b[8];
      *(float4*)&a[0] = *(const float4*)&sm.st.As[k][ty * 8];
      *(float4*)&a[4] = *(const float4*)&sm.st.As[k][ty * 8 + 4];
      *(float4*)&b[0] = *(const float4*)&sm.st.Bs[k][tx * 8];
      *(float4*)&b[4] = *(const float4*)&sm.st.Bs[k][tx * 8 + 4];
      #pragma unroll
      for (int r = 0; r < 8; ++r)
        #pragma unroll
        for (int c = 0; c < 8; ++c)
          acc[r][c] = fmaf(a[r], b[c], acc[r][c]);
    }
  }
  __syncthreads();
  float e2v[8];
  #pragma unroll
  for (int c = 0; c < 8; ++c) e2v[c] = e2[col0 + tx * 8 + c];
  #pragma unroll
  for (int r = 0; r < 8; ++r) {
    u64 bk = ~0ull;
    #pragma unroll
    for (int c = 0; c < 8; ++c) {
      int col = col0 + tx * 8 + c;
      float d = fmaf(-2.0f, acc[r][c], e2v[c]);
      u64 key = ((u64)sortable(d) << 32) | (u32)col;
      bk = key < bk ? key : bk;
    }
    sm.red[(ty * 8 + r) * 16 + tx] = bk;
  }
  __syncthreads();
  if (tid < 128) {
    u64 m = sm.red[tid * 16];
    #pragma unroll
    for (int t2 = 1; t2 < 16; ++t2) {
      u64 v = sm.red[tid * 16 + t2];
      m = v < m ? v : m;
    }
    atomicMin(&best[row0 + tid], m);
  }
}

// ---------- tail kernels ----------

__global__ __launch_bounds__(256) void scatter_kernel(const u64* __restrict__ best,
                                                      int* __restrict__ idx,
                                                      int* __restrict__ counts,
                                                      float* __restrict__ enc) {
  int i = blockIdx.x * 256 + threadIdx.x;
  u64 k = best[i];
  int j = (int)(k & 0xffffffffu);
  idx[i] = j;
  atomicAdd(&counts[j], 1);
  enc[(size_t)i * ENUM_ + j] = 1.0f;
}

__global__ __launch_bounds__(256) void gather_loss(const float* __restrict__ x,
                                                   const float* __restrict__ w,
                                                   const int* __restrict__ idx,
                                                   float* __restrict__ quant,
                                                   double* __restrict__ accum) {
  int i = blockIdx.x;
  int j = idx[i];
  const float4* wr = (const float4*)(w + (size_t)j * KD);
  const float4* xr = (const float4*)(x + (size_t)i * KD);
  float* qr = quant + (size_t)i * KD;
  double local = 0.0;
  #pragma unroll
  for (int t = 0; t < 4; ++t) {
    int e = threadIdx.x + t * 256;
    float4 wv = wr[e];
    float4 xv = xr[e];
    qr[4 * e + 0] = wv.x; qr[4 * e + 1] = wv.y;
    qr[4 * e + 2] = wv.z; qr[4 * e + 3] = wv.w;
    double d0 = (double)wv.x - (double)xv.x;
    double d1 = (double)wv.y - (double)xv.y;
    double d2 = (double)wv.z - (double)xv.z;
    double d3 = (double)wv.w - (double)xv.w;
    local += d0 * d0 + d1 * d1 + d2 * d2 + d3 * d3;
  }
  double tot = blockReduceSumD(local);
  if (threadIdx.x == 0) atomicAdd(accum, tot);
}

__global__ __launch_bounds__(256) void scalars_kernel(const int* __restrict__ counts,
                                                      const double* __restrict__ accum,
                                                      float* __restrict__ loss_out,
                                                      float* __restrict__ perp_out) {
  double local = 0.0;
  for (int j = threadIdx.x; j < ENUM_; j += 256) {
    double p = (double)counts[j] * (1.0 / 4096.0);
    local += p * log(p + 1e-10);
  }
  double s = blockReduceSumD(local);
  if (threadIdx.x == 0) {
    double mean = (*accum) * (1.0 / ((double)BROWS * (double)KD));
    loss_out[0] = (float)(1.25 * mean);
    perp_out[0] = (float)exp(-s);
  }
}

// ---------- launch ----------

extern "C" void kernel_launch(void* const* d_in, const int* in_sizes, int n_in,
                              void* d_out, int out_size, void* d_ws, size_t ws_size,
                              hipStream_t stream) {
  const float* x = (const float*)d_in[0];  // [4096][4096]
  const float* w = (const float*)d_in[1];  // [16384][4096]
  float* out = (float*)d_out;

  char* ws = (char*)d_ws;
  u64* best     = (u64*)ws;                    // 32768
  u64* best2    = (u64*)(ws + 32768);          // 32768
  int* idx      = (int*)(ws + 65536);          // 16384
  int* counts   = (int*)(ws + 81920);          // 65536
  double* accum = (double*)(ws + 147456);      // 8
  int* ccount   = (int*)(ws + 147464);         // 4
  float* e2     = (float*)(ws + 163840);       // 65536
  u64* cand     = (u64*)(ws + 229376);         // 524288

  // i8 filter-refine layout
  signed char* x_q = (signed char*)(ws + 753664);              // 16777216
  signed char* w_q = (signed char*)(ws + 17530880);            // 67108864
  float* s_x    = (float*)(ws + 84639744);     // 16384
  float* s_w    = (float*)(ws + 84656128);     // 65536
  u16* dist     = (u16*)(ws + 84721664);       // 134217728 (bf16 d-hat)
  const size_t NEED_FR = 84721664ull + 134217728ull;   // ~209 MB

  // legacy fallback layout (3-term bf16 / fp32)
  u16* x_hi     = (u16*)(ws + 753664);                 // 33554432
  u16* w_hi     = (u16*)(ws + 753664 + 33554432ull);   // 134217728
  char* regionO = ws + 753664 + 33554432ull + 134217728ull;  // 168525824
  u16* x_lo     = (u16*)regionO;               // 33554432
  u16* w_lo     = (u16*)(regionO + 33554432ull);       // 134217728
  const size_t NEED_3T = 168525824ull + 167772160ull;  // ~336 MB

  float* loss_out = out;
  float* quant    = out + 1;
  float* perp_out = out + 16777217;
  float* enc      = out + 16777218;

  hipMemsetAsync(best, 0xFF, 65536, stream);            // best + best2
  hipMemsetAsync(counts, 0, 65536 + 16, stream);        // counts + accum + ccount
  hipMemsetAsync(enc, 0, (size_t)BROWS * ENUM_ * sizeof(float), stream);

  if (ws_size >= NEED_FR) {
    quant_x<<<BROWS, 256, 0, stream>>>(x, x_q, s_x);
    quant_w_e2<<<ENUM_, 256, 0, stream>>>(w, w_q, s_w, e2);
    gemm_i8<<<1024, 512, 0, stream>>>(x_q, w_q, s_x, s_w, e2, dist, best);
    scan_kernel<<<4096, 256, 0, stream>>>(dist, best, cand, ccount);
    refine_kernel<<<4096, 256, 0, stream>>>(x, w, cand, ccount, best2);
    scatter_kernel<<<BROWS / 256, 256, 0, stream>>>(best2, idx, counts, enc);
  } else if (ws_size >= NEED_3T) {
    e2_kernel<<<ENUM_, 256, 0, stream>>>(w, e2);
    split_kernel<<<BROWS * KD / 8 / 256, 256, 0, stream>>>(x, x_hi, x_lo, BROWS * KD / 8);
    split_kernel<<<ENUM_ * KD / 8 / 256, 256, 0, stream>>>(w, w_hi, w_lo, ENUM_ * KD / 8);
    gemm_argmin_mfma<<<dim3(32, 128), 256, 0, stream>>>(x_hi, x_lo, w_hi, w_lo, e2, best);
    scatter_kernel<<<BROWS / 256, 256, 0, stream>>>(best, idx, counts, enc);
  } else {
    e2_kernel<<<ENUM_, 256, 0, stream>>>(w, e2);
    gemm_argmin<<<dim3(32, 128), 256, 0, stream>>>(x, w, e2, best);
    scatter_kernel<<<BROWS / 256, 256, 0, stream>>>(best, idx, counts, enc);
  }
  gather_loss<<<BROWS, 256, 0, stream>>>(x, w, idx, quant, accum);
  scalars_kernel<<<1, 256, 0, stream>>>(counts, accum, loss_out, perp_out);
}

// Round 3
// 1044.380 us; speedup vs baseline: 1.3290x; 1.0200x over previous
//
#include <hip/hip_runtime.h>

typedef unsigned long long u64;
typedef unsigned int u32;
typedef unsigned short u16;

typedef __attribute__((ext_vector_type(8))) short short8;
typedef __attribute__((ext_vector_type(4))) short short4v;
typedef __attribute__((ext_vector_type(4))) float floatx4;
typedef __attribute__((ext_vector_type(4))) int int4v;
typedef float float4a __attribute__((ext_vector_type(4), aligned(4)));

static constexpr int BROWS = 4096;   // batch rows (M)
static constexpr int ENUM_ = 16384;  // num embeddings (N)
static constexpr int KD    = 4096;   // embedding dim (K)
static constexpr int CANDMAX = 65536;
#define MARGIN 6e-4f

// ---------- helpers ----------

__device__ __forceinline__ u32 sortable(float d) {
  u32 u = __float_as_uint(d);
  return (u & 0x80000000u) ? ~u : (u | 0x80000000u);
}
__device__ __forceinline__ float unsortable(u32 k) {
  u32 u = (k & 0x80000000u) ? (k & 0x7fffffffu) : ~k;
  return __uint_as_float(u);
}

__device__ __forceinline__ u16 f2bf_rn(float f) {
  u32 u = __float_as_uint(f);
  u32 r = (u + 0x7fffu + ((u >> 16) & 1u)) >> 16;   // RNE (no NaNs in data)
  return (u16)r;
}
__device__ __forceinline__ float bf2f(u16 h) {
  return __uint_as_float((u32)h << 16);
}

__device__ __forceinline__ void gload_lds16(const void* g, void* l) {
  __builtin_amdgcn_global_load_lds((const __attribute__((address_space(1))) void*)g,
                                   (__attribute__((address_space(3))) void*)l,
                                   16, 0, 0);
}

__device__ __forceinline__ float blockReduceSumF(float v) {
  __shared__ float s[4];
  #pragma unroll
  for (int o = 32; o > 0; o >>= 1) v += __shfl_down(v, o);
  int lane = threadIdx.x & 63, wid = threadIdx.x >> 6;
  if (lane == 0) s[wid] = v;
  __syncthreads();
  float r = 0.f;
  if (threadIdx.x == 0) r = s[0] + s[1] + s[2] + s[3];
  return r;
}

__device__ __forceinline__ double blockReduceSumD(double v) {
  __shared__ double s[4];
  #pragma unroll
  for (int o = 32; o > 0; o >>= 1) v += __shfl_down(v, o);
  int lane = threadIdx.x & 63, wid = threadIdx.x >> 6;
  if (lane == 0) s[wid] = v;
  __syncthreads();
  double r = 0.0;
  if (threadIdx.x == 0) r = s[0] + s[1] + s[2] + s[3];
  return r;
}

// ---------- precompute kernels (i8 filter path) ----------

// x: fp32 -> per-row symmetric int8, sx[i] = rowmax/127
__global__ __launch_bounds__(256) void quant_x(const float* __restrict__ x,
                                               signed char* __restrict__ xq,
                                               float* __restrict__ sx) {
  int i = blockIdx.x;
  const float4* xr = (const float4*)(x + (size_t)i * KD);
  float4 v[4];
  float mx = 0.f;
  #pragma unroll
  for (int t = 0; t < 4; ++t) {
    v[t] = xr[threadIdx.x + t * 256];
    mx = fmaxf(mx, fmaxf(fmaxf(fabsf(v[t].x), fabsf(v[t].y)),
                         fmaxf(fabsf(v[t].z), fabsf(v[t].w))));
  }
  #pragma unroll
  for (int o = 32; o > 0; o >>= 1) mx = fmaxf(mx, __shfl_down(mx, o));
  __shared__ float red[4];
  int lane = threadIdx.x & 63, wid = threadIdx.x >> 6;
  if (lane == 0) red[wid] = mx;
  __syncthreads();
  float m = fmaxf(fmaxf(red[0], red[1]), fmaxf(red[2], red[3]));
  float inv = m > 0.f ? 127.f / m : 0.f;
  u32* qr = (u32*)(xq + (size_t)i * KD);
  #pragma unroll
  for (int t = 0; t < 4; ++t) {
    int e = threadIdx.x + t * 256;
    int q0 = __float2int_rn(v[t].x * inv);
    int q1 = __float2int_rn(v[t].y * inv);
    int q2 = __float2int_rn(v[t].z * inv);
    int q3 = __float2int_rn(v[t].w * inv);
    qr[e] = ((u32)(q0 & 0xff)) | ((u32)(q1 & 0xff) << 8) |
            ((u32)(q2 & 0xff) << 16) | ((u32)(q3 & 0xff) << 24);
  }
  if (threadIdx.x == 0) sx[i] = m * (1.f / 127.f);
}

// w: fp32 -> per-row int8 + sw[j] + e2[j]=sum w^2 (fp32)
__global__ __launch_bounds__(256) void quant_w_e2(const float* __restrict__ w,
                                                  signed char* __restrict__ wq,
                                                  float* __restrict__ sw,
                                                  float* __restrict__ e2) {
  int j = blockIdx.x;
  const float4* wr = (const float4*)(w + (size_t)j * KD);
  float4 v[4];
  float mx = 0.f, s2 = 0.f;
  #pragma unroll
  for (int t = 0; t < 4; ++t) {
    v[t] = wr[threadIdx.x + t * 256];
    s2 += v[t].x * v[t].x + v[t].y * v[t].y + v[t].z * v[t].z + v[t].w * v[t].w;
    mx = fmaxf(mx, fmaxf(fmaxf(fabsf(v[t].x), fabsf(v[t].y)),
                         fmaxf(fabsf(v[t].z), fabsf(v[t].w))));
  }
  #pragma unroll
  for (int o = 32; o > 0; o >>= 1) {
    s2 += __shfl_down(s2, o);
    mx = fmaxf(mx, __shfl_down(mx, o));
  }
  __shared__ float redS[4], redM[4];
  int lane = threadIdx.x & 63, wid = threadIdx.x >> 6;
  if (lane == 0) { redS[wid] = s2; redM[wid] = mx; }
  __syncthreads();
  float m = fmaxf(fmaxf(redM[0], redM[1]), fmaxf(redM[2], redM[3]));
  float inv = m > 0.f ? 127.f / m : 0.f;
  u32* qr = (u32*)(wq + (size_t)j * KD);
  #pragma unroll
  for (int t = 0; t < 4; ++t) {
    int e = threadIdx.x + t * 256;
    int q0 = __float2int_rn(v[t].x * inv);
    int q1 = __float2int_rn(v[t].y * inv);
    int q2 = __float2int_rn(v[t].z * inv);
    int q3 = __float2int_rn(v[t].w * inv);
    qr[e] = ((u32)(q0 & 0xff)) | ((u32)(q1 & 0xff) << 8) |
            ((u32)(q2 & 0xff) << 16) | ((u32)(q3 & 0xff) << 24);
  }
  if (threadIdx.x == 0) {
    sw[j] = m * (1.f / 127.f);
    e2[j] = redS[0] + redS[1] + redS[2] + redS[3];
  }
}

// fp32 -> bf16 hi + lo (3-term fallback)
__global__ __launch_bounds__(256) void split_kernel(const float* __restrict__ src,
                                                    u16* __restrict__ hi,
                                                    u16* __restrict__ lo, int n8) {
  int t = blockIdx.x * 256 + threadIdx.x;
  if (t >= n8) return;
  const float4* s = (const float4*)src + (size_t)t * 2;
  float4 a = s[0], b = s[1];
  float v[8] = {a.x, a.y, a.z, a.w, b.x, b.y, b.z, b.w};
  short h[8], l[8];
  #pragma unroll
  for (int i = 0; i < 8; ++i) {
    u16 hh = f2bf_rn(v[i]);
    h[i] = (short)hh;
    l[i] = (short)f2bf_rn(v[i] - bf2f(hh));
  }
  *(short8*)(hi + (size_t)t * 8) = *(short8*)h;
  *(short8*)(lo + (size_t)t * 8) = *(short8*)l;
}

// e2 standalone (fallback paths)
__global__ __launch_bounds__(256) void e2_kernel(const float* __restrict__ w,
                                                 float* __restrict__ e2) {
  int j = blockIdx.x;
  const float4* wr = (const float4*)(w + (size_t)j * KD);
  float local = 0.f;
  #pragma unroll
  for (int t = 0; t < 4; ++t) {
    float4 v = wr[threadIdx.x + t * 256];
    local += v.x * v.x + v.y * v.y + v.z * v.z + v.w * v.w;
  }
  float tot = blockReduceSumF(local);
  if (threadIdx.x == 0) e2[j] = tot;
}

// ---------- pass 1: i8 MFMA GEMM, 256x256 tile, BK=128, 2 phases/tile ------
// 512 thr = 8 waves (2Mx4N), per-wave out 128x64. Each phase = one M-half,
// full K=128: 32 MFMA (mfma_i32_16x16x64_i8, ~20.4 cy/SIMD each) per wave
// -> per-SIMD MFMA region ~1306 cy vs ~500 cy phase overhead (was 653/1060
// at 4 phases/tile -> MfmaUtil 33%). B frags ds_read once per tile (ph0),
// register-reused in ph1. LDS: 2 x 64 KB double buffer; region = 256 rows x
// 128 B; chunk c at byte c*16, row=c>>3, slot=c&7 holds source chunk
// slot^(row&7) -> frag ds_read_b128 is 2 lanes/slot (free); DMA dest linear.
// DMA ledger (regions by consumption): A0={rows 0-63,128-191} & B consumed
// ph0; A1 consumed ph1. Issue A1(t+1) in ph0 (2 gloads), A0/B(t+2) in ph1
// (6 gloads). vmcnt(6) at tile end -> tile t+1 fully landed (peak 14
// outstanding); last two tiles vmcnt(0). Every region has consuming-MFMA
// (compiler lgkm wait) + barrier between last read and next DMA issue.
__global__ __launch_bounds__(512, 2)
void gemm_i8(const signed char* __restrict__ Aq, const signed char* __restrict__ Bq,
             const float* __restrict__ sx, const float* __restrict__ sw,
             const float* __restrict__ e2, u16* __restrict__ dist,
             u64* __restrict__ best) {
  __shared__ char smem[131072];
  constexpr int NT = KD / 128;  // 32 K-tiles

  const u32 wg = blockIdx.x;
  const u32 swz = (wg & 7) * 128 + (wg >> 3);   // XCD-bijective (1024 % 8 == 0)
  const int by = swz & 15;
  const int bx = swz >> 4;
  const int row0 = by * 256, col0 = bx * 256;

  const int t = threadIdx.x;
  const int lane = t & 63, wv = t >> 6;
  const int wr = wv >> 2, wc = wv & 3;
  const int quad = lane >> 4, lcol = lane & 15;

  // staging: call q covers rows q*64..q*64+63; per-thread row = q*64+(t>>3),
  // slot = t&7, source chunk g = slot ^ (row&7) = (t&7)^((t>>3)&7).
  const int srow = t >> 3;
  const int g0 = (t & 7) ^ ((t >> 3) & 7);
  const size_t aBase = (size_t)(row0 + srow) * KD + g0 * 16;
  const size_t bBase = (size_t)(col0 + srow) * KD + g0 * 16;

  auto stageA = [&](int tau, int q) {
    if (tau >= NT) return;
    gload_lds16(Aq + aBase + (size_t)(q * 64) * KD + (size_t)tau * 128,
                smem + (tau & 1) * 65536 + q * 8192 + t * 16);
  };
  auto stageB = [&](int tau, int q) {
    if (tau >= NT) return;
    gload_lds16(Bq + bBase + (size_t)(q * 64) * KD + (size_t)tau * 128,
                smem + (tau & 1) * 65536 + 32768 + q * 8192 + t * 16);
  };

  // prologue: tile0 full (8 gloads), tile1 A0+B (6 gloads)
  stageA(0, 0); stageA(0, 1); stageA(0, 2); stageA(0, 3);
  stageB(0, 0); stageB(0, 1); stageB(0, 2); stageB(0, 3);
  stageA(1, 0); stageA(1, 2);
  stageB(1, 0); stageB(1, 1); stageB(1, 2); stageB(1, 3);
  asm volatile("s_waitcnt vmcnt(6)" ::: "memory");   // tile 0 landed
  asm volatile("s_barrier" ::: "memory");

  int4v acc[8][4] = {};

  for (int tt = 0; tt < NT; ++tt) {
    const char* Ar = smem + (tt & 1) * 65536;
    const char* Br = Ar + 32768;
    int4v af[4][2], bf[4][2];

    // ---- phase 0: M-half 0, full K=128 ----
    #pragma unroll
    for (int r = 0; r < 4; ++r) {
      int m = wr * 128 + r * 16 + lcol;
      #pragma unroll
      for (int k = 0; k < 2; ++k)
        af[r][k] = *(const int4v*)(Ar + m * 128 + ((((k << 2) | quad) ^ (m & 7)) << 4));
    }
    #pragma unroll
    for (int n = 0; n < 4; ++n) {
      int mm = wc * 64 + n * 16 + lcol;
      #pragma unroll
      for (int k = 0; k < 2; ++k)
        bf[n][k] = *(const int4v*)(Br + mm * 128 + ((((k << 2) | quad) ^ (mm & 7)) << 4));
    }
    stageA(tt + 1, 1); stageA(tt + 1, 3);   // A1(t+1) -> other buffer
    asm volatile("s_barrier" ::: "memory");
    __builtin_amdgcn_s_setprio(1);
    #pragma unroll
    for (int k = 0; k < 2; ++k)
      #pragma unroll
      for (int r = 0; r < 4; ++r)
        #pragma unroll
        for (int n = 0; n < 4; ++n)
          acc[r][n] = __builtin_amdgcn_mfma_i32_16x16x64_i8(
              af[r][k], bf[n][k], acc[r][n], 0, 0, 0);
    __builtin_amdgcn_s_setprio(0);
    asm volatile("s_barrier" ::: "memory");

    // ---- phase 1: M-half 1, full K=128 (bf reused from registers) ----
    #pragma unroll
    for (int r = 0; r < 4; ++r) {
      int m = wr * 128 + 64 + r * 16 + lcol;
      #pragma unroll
      for (int k = 0; k < 2; ++k)
        af[r][k] = *(const int4v*)(Ar + m * 128 + ((((k << 2) | quad) ^ (m & 7)) << 4));
    }
    if (tt < NT - 2) {
      stageA(tt + 2, 0); stageA(tt + 2, 2);   // A0(t+2) -> this buffer
      stageB(tt + 2, 0); stageB(tt + 2, 1); stageB(tt + 2, 2); stageB(tt + 2, 3);
    }
    asm volatile("s_barrier" ::: "memory");
    __builtin_amdgcn_s_setprio(1);
    #pragma unroll
    for (int k = 0; k < 2; ++k)
      #pragma unroll
      for (int r = 0; r < 4; ++r)
        #pragma unroll
        for (int n = 0; n < 4; ++n)
          acc[4 + r][n] = __builtin_amdgcn_mfma_i32_16x16x64_i8(
              af[r][k], bf[n][k], acc[4 + r][n], 0, 0, 0);
    __builtin_amdgcn_s_setprio(0);
    if (tt < NT - 2) asm volatile("s_waitcnt vmcnt(6)" ::: "memory");
    else             asm volatile("s_waitcnt vmcnt(0)" ::: "memory");
    asm volatile("s_barrier" ::: "memory");
  }

  // epilogue: d = e2[j] - 2*sx[i]*sw[j]*dot. C/D: col=lane&15, row=quad*4+reg.
  // acc[fm] with fm=mh*4+r maps to row wr*128 + fm*16 (identity holds).
  float e2v[4], sc2[4];
  #pragma unroll
  for (int n = 0; n < 4; ++n) {
    int gc = col0 + wc * 64 + n * 16 + lcol;
    e2v[n] = e2[gc];
    sc2[n] = -2.0f * sw[gc];
  }

  #pragma unroll
  for (int fm = 0; fm < 8; ++fm) {
    #pragma unroll
    for (int i = 0; i < 4; ++i) {
      int grow = row0 + wr * 128 + fm * 16 + quad * 4 + i;
      float sxr = sx[grow];
      u64 kmin = ~0ull;
      #pragma unroll
      for (int n = 0; n < 4; ++n) {
        int gcol = col0 + wc * 64 + n * 16 + lcol;
        float d = __fadd_rn(e2v[n],
                            __fmul_rn(sc2[n] * sxr, (float)acc[fm][n][i]));
        dist[(size_t)grow * ENUM_ + gcol] = f2bf_rn(d);
        u64 key = ((u64)sortable(d) << 32) | (u32)gcol;
        kmin = key < kmin ? key : kmin;
      }
      #pragma unroll
      for (int msk = 1; msk < 16; msk <<= 1) {
        u64 o = __shfl_xor(kmin, msk);
        kmin = o < kmin ? o : kmin;
      }
      if (lcol == 0) atomicMin(&best[grow], kmin);
    }
  }
}

// ---------- pass 2: scan bf16 d-hat, emit candidates within margin ----------
__global__ __launch_bounds__(256)
void scan_kernel(const u16* __restrict__ dist, const u64* __restrict__ best,
                 u64* __restrict__ cand, int* __restrict__ ccount) {
  const int n8 = BROWS * ENUM_ / 8;
  int step = gridDim.x * 256;
  for (int f = blockIdx.x * 256 + threadIdx.x; f < n8; f += step) {
    int i = f >> 11;                       // 2048 short8 per row
    float limit = unsortable((u32)(best[i] >> 32)) + MARGIN;
    short8 v = ((const short8*)dist)[f];
    #pragma unroll
    for (int e = 0; e < 8; ++e) {
      float d = bf2f((u16)v[e]);
      if (d <= limit) {
        int pos = atomicAdd(ccount, 1);
        if (pos < CANDMAX) cand[pos] = ((u64)(u32)i << 32) | (u32)(f * 8 + e - i * ENUM_);
      }
    }
  }
}

// ---------- pass 3: exact fp64 rescore of candidates ----------
__global__ __launch_bounds__(256)
void refine_kernel(const float* __restrict__ x, const float* __restrict__ w,
                   const u64* __restrict__ cand, const int* __restrict__ ccount,
                   u64* __restrict__ best2) {
  int cnt = *ccount;
  if (cnt > CANDMAX) cnt = CANDMAX;
  for (int b = blockIdx.x; b < cnt; b += gridDim.x) {
    u64 cd = cand[b];
    int i = (int)(cd >> 32), j = (int)(cd & 0xffffffffu);
    const float4* xr = (const float4*)(x + (size_t)i * KD);
    const float4* wr = (const float4*)(w + (size_t)j * KD);
    double local = 0.0;
    #pragma unroll
    for (int t = 0; t < 4; ++t) {
      int e = threadIdx.x + t * 256;
      float4 xv = xr[e], wv = wr[e];
      local += (double)wv.x * ((double)wv.x - 2.0 * (double)xv.x)
             + (double)wv.y * ((double)wv.y - 2.0 * (double)xv.y)
             + (double)wv.z * ((double)wv.z - 2.0 * (double)xv.z)
             + (double)wv.w * ((double)wv.w - 2.0 * (double)xv.w);
    }
    double d = blockReduceSumD(local);
    if (threadIdx.x == 0) {
      u64 key = ((u64)sortable((float)d) << 32) | (u32)j;
      atomicMin(&best2[i], key);
    }
    __syncthreads();
  }
}

// ---------- 3-term fallback GEMM ----------
__global__ __launch_bounds__(256)
void gemm_argmin_mfma(const u16* __restrict__ Ah, const u16* __restrict__ Al,
                      const u16* __restrict__ Bh, const u16* __restrict__ Bl,
                      const float* __restrict__ e2, u64* __restrict__ best) {
  __shared__ char smem[32768];
  const int by = blockIdx.x, bx = blockIdx.y;
  const int row0 = by * 128, col0 = bx * 128;
  const int t = threadIdx.x;
  const int lane = t & 63, wv = t >> 6;
  const int wr = wv >> 1, wc = wv & 1;
  const int srow = t >> 2;
  const int schunk = (t & 3) ^ ((t >> 3) & 3);
  const size_t aoff0 = (size_t)(row0 + srow) * KD + schunk * 8;
  const size_t aoff1 = aoff0 + (size_t)64 * KD;
  const size_t boff0 = (size_t)(col0 + srow) * KD + schunk * 8;
  const size_t boff1 = boff0 + (size_t)64 * KD;
  char* sAh = smem; char* sAl = smem + 8192;
  char* sBh = smem + 16384; char* sBl = smem + 24576;
  const int d0 = t * 16, d1 = 4096 + t * 16;
  floatx4 acc[4][4] = {};
  for (int kk = 0; kk < KD; kk += 32) {
    __syncthreads();
    gload_lds16(Ah + aoff0 + kk, sAh + d0);
    gload_lds16(Ah + aoff1 + kk, sAh + d1);
    gload_lds16(Al + aoff0 + kk, sAl + d0);
    gload_lds16(Al + aoff1 + kk, sAl + d1);
    gload_lds16(Bh + boff0 + kk, sBh + d0);
    gload_lds16(Bh + boff1 + kk, sBh + d1);
    gload_lds16(Bl + boff0 + kk, sBl + d0);
    gload_lds16(Bl + boff1 + kk, sBl + d1);
    __syncthreads();
    short8 afh[4], afl[4];
    #pragma unroll
    for (int r = 0; r < 4; ++r) {
      int m = wr * 64 + r * 16 + (lane & 15);
      int off = m * 64 + (((lane >> 4) ^ ((m >> 1) & 3)) * 16);
      afh[r] = *(const short8*)(sAh + off);
      afl[r] = *(const short8*)(sAl + off);
    }
    #pragma unroll
    for (int c = 0; c < 4; ++c) {
      int m = wc * 64 + c * 16 + (lane & 15);
      int off = m * 64 + (((lane >> 4) ^ ((m >> 1) & 3)) * 16);
      short8 bfh = *(const short8*)(sBh + off);
      short8 bfl = *(const short8*)(sBl + off);
      #pragma unroll
      for (int r = 0; r < 4; ++r) {
        acc[r][c] = __builtin_amdgcn_mfma_f32_16x16x32_bf16(afh[r], bfh, acc[r][c], 0, 0, 0);
        acc[r][c] = __builtin_amdgcn_mfma_f32_16x16x32_bf16(afl[r], bfh, acc[r][c], 0, 0, 0);
        acc[r][c] = __builtin_amdgcn_mfma_f32_16x16x32_bf16(afh[r], bfl, acc[r][c], 0, 0, 0);
      }
    }
  }
  const int quad = lane >> 4, lcol = lane & 15;
  float e2v[4];
  #pragma unroll
  for (int c = 0; c < 4; ++c) e2v[c] = e2[col0 + wc * 64 + c * 16 + lcol];
  #pragma unroll
  for (int r = 0; r < 4; ++r) {
    #pragma unroll
    for (int i = 0; i < 4; ++i) {
      int grow = row0 + wr * 64 + r * 16 + quad * 4 + i;
      u64 kmin = ~0ull;
      #pragma unroll
      for (int c = 0; c < 4; ++c) {
        int gcol = col0 + wc * 64 + c * 16 + lcol;
        float d = __fadd_rn(e2v[c], __fmul_rn(-2.0f, acc[r][c][i]));
        u64 key = ((u64)sortable(d) << 32) | (u32)gcol;
        kmin = key < kmin ? key : kmin;
      }
      #pragma unroll
      for (int msk = 1; msk < 16; msk <<= 1) {
        u64 o = __shfl_xor(kmin, msk);
        kmin = o < kmin ? o : kmin;
      }
      if (lcol == 0) atomicMin(&best[grow], kmin);
    }
  }
}

// ---------- fp32 fallback GEMM ----------
__global__ __launch_bounds__(256)
void gemm_argmin(const float* __restrict__ A, const float* __restrict__ W,
                 const float* __restrict__ e2, u64* __restrict__ best) {
  __shared__ union {
    struct { float As[8][128]; float Bs[8][128]; } st;
    u64 red[128 * 16];
  } sm;
  const int by = blockIdx.x, bx = blockIdx.y;
  const int tid = threadIdx.x;
  const int tx = tid & 15, ty = tid >> 4;
  const int row0 = by * 128, col0 = bx * 128;
  const int lm = tid >> 1, lk = (tid & 1) * 4;
  const float* Ap = A + (size_t)(row0 + lm) * KD + lk;
  const float* Wp = W + (size_t)(col0 + lm) * KD + lk;
  float acc[8][8];
  #pragma unroll
  for (int r = 0; r < 8; ++r)
    #pragma unroll
    for (int c = 0; c < 8; ++c) acc[r][c] = 0.f;
  for (int kk = 0; kk < KD; kk += 8) {
    float4 av = *(const float4*)(Ap + kk);
    float4 bv = *(const float4*)(Wp + kk);
    __syncthreads();
    sm.st.As[lk + 0][lm] = av.x; sm.st.As[lk + 1][lm] = av.y;
    sm.st.As[lk + 2][lm] = av.z; sm.st.As[lk + 3][lm] = av.w;
    sm.st.Bs[lk + 0][lm] = bv.x; sm.st.Bs[lk + 1][lm] = bv.y;
    sm.st.Bs[lk + 2][lm] = bv.z; sm.st.Bs[lk + 3][lm] = bv.w;
    __syncthreads();
    #pragma unroll
    for (int k = 0; k < 8; ++k) {
      float a[8], b[8];
      *(float4*)&a[0] = *(const float4*)&sm.st.As[k][ty * 8];
      *(float4*)&a[4] = *(const float4*)&sm.st.As[k][ty * 8 + 4];
      *(float4*)&b[0] = *(const float4*)&sm.st.Bs[k][tx * 8];
      *(float4*)&b[4] = *(const float4*)&sm.st.Bs[k][tx * 8 + 4];
      #pragma unroll
      for (int r = 0; r < 8; ++r)
        #pragma unroll
        for (int c = 0; c < 8; ++c)
          acc[r][c] = fmaf(a[r], b[c], acc[r][c]);
    }
  }
  __syncthreads();
  float e2v[8];
  #pragma unroll
  for (int c = 0; c < 8; ++c) e2v[c] = e2[col0 + tx * 8 + c];
  #pragma unroll
  for (int r = 0; r < 8; ++r) {
    u64 bk = ~0ull;
    #pragma unroll
    for (int c = 0; c < 8; ++c) {
      int col = col0 + tx * 8 + c;
      float d = fmaf(-2.0f, acc[r][c], e2v[c]);
      u64 key = ((u64)sortable(d) << 32) | (u32)col;
      bk = key < bk ? key : bk;
    }
    sm.red[(ty * 8 + r) * 16 + tx] = bk;
  }
  __syncthreads();
  if (tid < 128) {
    u64 m = sm.red[tid * 16];
    #pragma unroll
    for (int t2 = 1; t2 < 16; ++t2) {
      u64 v = sm.red[tid * 16 + t2];
      m = v < m ? v : m;
    }
    atomicMin(&best[row0 + tid], m);
  }
}

// ---------- tail kernels ----------

// fused: zero one enc row + set one-hot + idx + counts (replaces 256 MB
// memset dispatch + scatter kernel)
__global__ __launch_bounds__(256) void enc_fill(const u64* __restrict__ best,
                                                int* __restrict__ idx,
                                                int* __restrict__ counts,
                                                float* __restrict__ enc) {
  int i = blockIdx.x;
  u64 k = best[i];
  int j = (int)(k & 0xffffffffu);
  if (threadIdx.x == 0) {
    idx[i] = j;
    atomicAdd(&counts[j], 1);
  }
  float* er = enc + (size_t)i * ENUM_;   // base is 8 mod 16 B -> align(4) stores
  #pragma unroll
  for (int tq = 0; tq < 16; ++tq) {
    int e = threadIdx.x + tq * 256;      // float4 index, 4096 per row
    float4a z = {0.f, 0.f, 0.f, 0.f};
    int base = e * 4;
    if ((j >> 2) == e) z[j & 3] = 1.0f;
    *(float4a*)(er + base) = z;
  }
}

__global__ __launch_bounds__(256) void gather_loss(const float* __restrict__ x,
                                                   const float* __restrict__ w,
                                                   const int* __restrict__ idx,
                                                   float* __restrict__ quant,
                                                   double* __restrict__ accum) {
  int i = blockIdx.x;
  int j = idx[i];
  const float4* wr = (const float4*)(w + (size_t)j * KD);
  const float4* xr = (const float4*)(x + (size_t)i * KD);
  float* qr = quant + (size_t)i * KD;    // 4 mod 16 B -> align(4) stores
  double local = 0.0;
  #pragma unroll
  for (int t = 0; t < 4; ++t) {
    int e = threadIdx.x + t * 256;
    float4 wv = wr[e];
    float4 xv = xr[e];
    float4a q; q[0] = wv.x; q[1] = wv.y; q[2] = wv.z; q[3] = wv.w;
    *(float4a*)(qr + 4 * e) = q;
    double d0 = (double)wv.x - (double)xv.x;
    double d1 = (double)wv.y - (double)xv.y;
    double d2 = (double)wv.z - (double)xv.z;
    double d3 = (double)wv.w - (double)xv.w;
    local += d0 * d0 + d1 * d1 + d2 * d2 + d3 * d3;
  }
  double tot = blockReduceSumD(local);
  if (threadIdx.x == 0) atomicAdd(accum, tot);
}

__global__ __launch_bounds__(256) void scalars_kernel(const int* __restrict__ counts,
                                                      const double* __restrict__ accum,
                                                      float* __restrict__ loss_out,
                                                      float* __restrict__ perp_out) {
  double local = 0.0;
  for (int j = threadIdx.x; j < ENUM_; j += 256) {
    double p = (double)counts[j] * (1.0 / 4096.0);
    local += p * (double)__logf((float)(p + 1e-10));
  }
  double s = blockReduceSumD(local);
  if (threadIdx.x == 0) {
    double mean = (*accum) * (1.0 / ((double)BROWS * (double)KD));
    loss_out[0] = (float)(1.25 * mean);
    perp_out[0] = (float)exp(-s);
  }
}

// ---------- launch ----------

extern "C" void kernel_launch(void* const* d_in, const int* in_sizes, int n_in,
                              void* d_out, int out_size, void* d_ws, size_t ws_size,
                              hipStream_t stream) {
  const float* x = (const float*)d_in[0];  // [4096][4096]
  const float* w = (const float*)d_in[1];  // [16384][4096]
  float* out = (float*)d_out;

  char* ws = (char*)d_ws;
  u64* best     = (u64*)ws;                    // 32768
  u64* best2    = (u64*)(ws + 32768);          // 32768
  int* idx      = (int*)(ws + 65536);          // 16384
  int* counts   = (int*)(ws + 81920);          // 65536
  double* accum = (double*)(ws + 147456);      // 8
  int* ccount   = (int*)(ws + 147464);         // 4
  float* e2     = (float*)(ws + 163840);       // 65536
  u64* cand     = (u64*)(ws + 229376);         // 524288

  // i8 filter-refine layout
  signed char* x_q = (signed char*)(ws + 753664);              // 16777216
  signed char* w_q = (signed char*)(ws + 17530880);            // 67108864
  float* s_x    = (float*)(ws + 84639744);     // 16384
  float* s_w    = (float*)(ws + 84656128);     // 65536
  u16* dist     = (u16*)(ws + 84721664);       // 134217728 (bf16 d-hat)
  const size_t NEED_FR = 84721664ull + 134217728ull;   // ~209 MB

  // legacy fallback layout (3-term bf16 / fp32)
  u16* x_hi     = (u16*)(ws + 753664);                 // 33554432
  u16* w_hi     = (u16*)(ws + 753664 + 33554432ull);   // 134217728
  char* regionO = ws + 753664 + 33554432ull + 134217728ull;  // 168525824
  u16* x_lo     = (u16*)regionO;               // 33554432
  u16* w_lo     = (u16*)(regionO + 33554432ull);       // 134217728
  const size_t NEED_3T = 168525824ull + 167772160ull;  // ~336 MB

  float* loss_out = out;
  float* quant    = out + 1;
  float* perp_out = out + 16777217;
  float* enc      = out + 16777218;

  hipMemsetAsync(best, 0xFF, 65536, stream);            // best + best2
  hipMemsetAsync(counts, 0, 65536 + 16, stream);        // counts + accum + ccount

  if (ws_size >= NEED_FR) {
    quant_x<<<BROWS, 256, 0, stream>>>(x, x_q, s_x);
    quant_w_e2<<<ENUM_, 256, 0, stream>>>(w, w_q, s_w, e2);
    gemm_i8<<<1024, 512, 0, stream>>>(x_q, w_q, s_x, s_w, e2, dist, best);
    scan_kernel<<<4096, 256, 0, stream>>>(dist, best, cand, ccount);
    refine_kernel<<<4096, 256, 0, stream>>>(x, w, cand, ccount, best2);
    enc_fill<<<BROWS, 256, 0, stream>>>(best2, idx, counts, enc);
  } else if (ws_size >= NEED_3T) {
    e2_kernel<<<ENUM_, 256, 0, stream>>>(w, e2);
    split_kernel<<<BROWS * KD / 8 / 256, 256, 0, stream>>>(x, x_hi, x_lo, BROWS * KD / 8);
    split_kernel<<<ENUM_ * KD / 8 / 256, 256, 0, stream>>>(w, w_hi, w_lo, ENUM_ * KD / 8);
    gemm_argmin_mfma<<<dim3(32, 128), 256, 0, stream>>>(x_hi, x_lo, w_hi, w_lo, e2, best);
    enc_fill<<<BROWS, 256, 0, stream>>>(best, idx, counts, enc);
  } else {
    e2_kernel<<<ENUM_, 256, 0, stream>>>(w, e2);
    gemm_argmin<<<dim3(32, 128), 256, 0, stream>>>(x, w, e2, best);
    enc_fill<<<BROWS, 256, 0, stream>>>(best, idx, counts, enc);
  }
  gather_loss<<<BROWS, 256, 0, stream>>>(x, w, idx, quant, accum);
  scalars_kernel<<<1, 256, 0, stream>>>(counts, accum, loss_out, perp_out);
}